// Round 10
// baseline (449.727 us; speedup 1.0000x reference)
//
#include <hip/hip_runtime.h>
#include <hip/hip_bf16.h>

typedef __attribute__((ext_vector_type(4))) float  f32x4;
typedef __attribute__((ext_vector_type(8))) short  s16x8;
typedef __attribute__((ext_vector_type(4))) short  s16x4;

union BH4 { s16x4 v; __hip_bfloat16 h[4]; };
union BH8 { s16x8 v; __hip_bfloat16 h[8]; };

#define MFMA16(A,B,C) __builtin_amdgcn_mfma_f32_16x16x32_bf16((A),(B),(C),0,0,0)

__device__ __forceinline__ float sigm(float x) { return 1.0f / (1.0f + __expf(-x)); }

// [rows][256] bf16 (512 B rows): XOR row into 16B slot (bank-conflict fix)
__device__ __forceinline__ int xad(int r, int byteInRow) {
  return ((r << 9) + byteInRow) ^ ((r & 7) << 4);
}
// chunk buffers: [rows][64] bf16 (128 B rows): slot16 ^= (i&7)   (fallback path)
__device__ __forceinline__ int cad64(int i, int k) {
  return (i << 7) + ((((k >> 3) ^ (i & 7)) << 4) | ((k & 7) << 1));
}

// fp32 weight [256][256] -> bf16 MFMA B-fragment order:
// dst[((m*16+ct)*8+ks)*512 + lane*8 + j] = w[ct*16+(lane&15)][ks*32+(lane>>4)*8+j]
__global__ void wfrag_kernel(const float* __restrict__ w_in,
                             const float* __restrict__ w_gate,
                             const float* __restrict__ w_out,
                             __hip_bfloat16* __restrict__ dst) {
  const int lane = threadIdx.x;         // 64
  const int fid  = blockIdx.x;          // 0..127 = ct*8+ks
  const int m    = blockIdx.y;          // 0:wa 1:wb 2:wg 3:wo
  const float* src = (m == 0) ? w_in : (m == 1) ? (w_in + 65536)
                    : (m == 2) ? w_gate : w_out;
  const int e  = (fid >> 3) * 16 + (lane & 15);
  const int d0 = (fid & 7) * 32 + (lane >> 4) * 8;
  BH8 u;
  #pragma unroll
  for (int j = 0; j < 8; ++j) u.h[j] = __float2bfloat16(src[e * 256 + d0 + j]);
  *reinterpret_cast<s16x8*>(dst + (size_t)m * 65536 + ((size_t)fid * 64 + lane) * 8) = u.v;
}

// K1: x = LN(pair) -> xws in A-fragment order (proven):
// xws[((s*16+rt)*8+ks)*512 + lane*8 + j] = x[s][rt*16+(lane&15)][ks*32+(lane>>4)*8+j]
__global__ __launch_bounds__(256) void ln_kernel(
    const float* __restrict__ pair, const float* __restrict__ gamma,
    const float* __restrict__ beta, __hip_bfloat16* __restrict__ xws)
{
  __shared__ char Xl[8192];
  const int t  = threadIdx.x;
  const int s  = blockIdx.x >> 4;
  const int rt = blockIdx.x & 15;
  const int r  = t >> 4;
  const int c0 = (t & 15) * 16;
  const float* src = pair + (((size_t)s * 256 + rt * 16 + r) * 256 + c0);
  float v[16];
  #pragma unroll
  for (int i = 0; i < 4; ++i) {
    const float4 f = *reinterpret_cast<const float4*>(src + i * 4);
    v[i*4+0]=f.x; v[i*4+1]=f.y; v[i*4+2]=f.z; v[i*4+3]=f.w;
  }
  float sm = 0.f, ss = 0.f;
  #pragma unroll
  for (int i = 0; i < 16; ++i) { sm += v[i]; ss += v[i]*v[i]; }
  #pragma unroll
  for (int m = 1; m < 16; m <<= 1) { sm += __shfl_xor(sm, m); ss += __shfl_xor(ss, m); }
  const float mean = sm * (1.f/256.f);
  const float rstd = rsqrtf(ss * (1.f/256.f) - mean*mean + 1e-5f);
  #pragma unroll
  for (int i = 0; i < 4; ++i) {
    const float4 gm = *reinterpret_cast<const float4*>(gamma + c0 + i*4);
    const float4 bt = *reinterpret_cast<const float4*>(beta  + c0 + i*4);
    BH4 o;
    o.h[0] = __float2bfloat16((v[i*4+0]-mean)*rstd*gm.x + bt.x);
    o.h[1] = __float2bfloat16((v[i*4+1]-mean)*rstd*gm.y + bt.y);
    o.h[2] = __float2bfloat16((v[i*4+2]-mean)*rstd*gm.z + bt.z);
    o.h[3] = __float2bfloat16((v[i*4+3]-mean)*rstd*gm.w + bt.w);
    *reinterpret_cast<s16x4*>(Xl + xad(r, (c0 + i*4)*2)) = o.v;
  }
  __syncthreads();
  #pragma unroll
  for (int p = 0; p < 2; ++p) {
    const int u  = t + p * 256;
    const int ks = u >> 6;
    const int lp = u & 63;
    const s16x8 f = *reinterpret_cast<const s16x8*>(
        Xl + xad(lp & 15, ks*64 + ((lp>>4)&3)*16));
    *reinterpret_cast<s16x8*>(xws + ((((size_t)s*16 + rt)*8 + ks)*64 + lp)*8) = f;
  }
}

// ===================== STRATEGY A =====================
// K2: per-slice block (512 thr, 8 waves). Wave w owns token row-tiles 2w,2w+1
// (x A-frags from xws in regs). Weights broadcast via 2x8KB LDS double buffer.
// 32 cg tiles: a (SiLU->aT frags) and b (SiLU->bT frags).
__global__ __launch_bounds__(512, 4) void k2_ab(
    const __hip_bfloat16* __restrict__ xws,
    const __hip_bfloat16* __restrict__ wfrag,
    __hip_bfloat16* __restrict__ aT, __hip_bfloat16* __restrict__ bT)
{
  __shared__ __align__(16) char wb2[2][8192];
  const int raw = blockIdx.x;                    // 512 blocks
  const int s   = (raw & 7) * 64 + (raw >> 3);   // XCD-pinned slice
  const int tid = threadIdx.x, lane = tid & 63, w = tid >> 6;
  const int l15 = lane & 15, lh = lane >> 4;

  // x A-frags for this wave's two row-tiles (regs/AGPR, 64)
  s16x8 xr[2][8];
  #pragma unroll
  for (int rt = 0; rt < 2; ++rt)
    #pragma unroll
    for (int ks = 0; ks < 8; ++ks)
      xr[rt][ks] = *reinterpret_cast<const s16x8*>(
          xws + (((size_t)s*16 + (w*2 + rt))*8 + ks)*512 + lane*8);

  // preload cg=0 weight chunk (8 KB) into buffer 0
  {
    const s16x8 v0 = *reinterpret_cast<const s16x8*>(wfrag + tid*8);
    *reinterpret_cast<s16x8*>(&wb2[0][tid*16]) = v0;
  }
  __syncthreads();

  #pragma unroll 1
  for (int cg = 0; cg < 32; ++cg) {       // 0..15 = a ct, 16..31 = b ct
    const int cur = cg & 1;
    s16x8 pf;
    if (cg < 31)
      pf = *reinterpret_cast<const s16x8*>(wfrag + (size_t)(cg+1)*4096 + tid*8);

    const int m  = cg >> 4;
    const int ct = cg & 15;
    f32x4 acc0 = (f32x4){0.f,0.f,0.f,0.f};
    f32x4 acc1 = (f32x4){0.f,0.f,0.f,0.f};
    #pragma unroll
    for (int ks = 0; ks < 8; ++ks) {
      const s16x8 Bf = *reinterpret_cast<const s16x8*>(&wb2[cur][ks*1024 + lane*16]);
      acc0 = MFMA16(xr[0][ks], Bf, acc0);
      acc1 = MFMA16(xr[1][ks], Bf, acc1);
    }
    __hip_bfloat16* const dst = (m == 0) ? aT : bT;
    #pragma unroll
    for (int rt = 0; rt < 2; ++rt) {
      const f32x4 a = rt ? acc1 : acc0;
      BH4 o;
      #pragma unroll
      for (int q = 0; q < 4; ++q) o.h[q] = __float2bfloat16(a[q] * sigm(a[q]));
      const int lane2 = l15 + 16 * ((rt*2 + (lh >> 1)) & 3);
      // frag (s, it=ct, kt=w); value = act[k = w*32+rt*16+lh*4+q][i = ct*16+l15]
      *reinterpret_cast<s16x4*>(
          dst + (((size_t)s*16 + ct)*8 + w)*512 + lane2*8 + (lh & 1)*4) = o.v;
    }
    if (cg < 31)
      *reinterpret_cast<s16x8*>(&wb2[cur ^ 1][tid*16]) = pf;
    __syncthreads();
  }
}

// K3: half-slice block (128 i x 256 j), 512 thr, 8 waves.
// Wave (r2=w>>1, ch=w&1): tri rows r2*32..+32, cols ch*128..+128.
// tri = aT.bT via DOUBLE-BUFFERED frag-linear LDS staging (1 barrier/chunk);
// in-reg LN; out phase split G-then-O (register-disjoint, no spill).
__global__ __launch_bounds__(512, 4) void k3_tri(
    const __hip_bfloat16* __restrict__ aT, const __hip_bfloat16* __restrict__ bT,
    const __hip_bfloat16* __restrict__ xws, const __hip_bfloat16* __restrict__ wfrag,
    const float* __restrict__ gamma, const float* __restrict__ beta,
    float* __restrict__ out)
{
  extern __shared__ __align__(16) char lds[];    // 67584 B
  // STG double buffer: buf p at lds + p*24576, each 24 frags x 1KB
  char*  const SW  = lds;                        // 65536 overlay: ln(tri) [128][256]
  float* const ST  = (float*)(lds + 65536);      // 2048: LN stats exchange

  const int raw = blockIdx.x;                    // 1024 blocks
  const int s   = (raw & 7) * 64 + ((raw >> 3) >> 1);
  const int h   = (raw >> 3) & 1;
  const int tid = threadIdx.x, lane = tid & 63, w = tid >> 6;
  const int l15 = lane & 15, lh = lane >> 4;
  const int r2 = w >> 1, ch = w & 1;

  f32x4 tri[2][8];
  #pragma unroll
  for (int rt = 0; rt < 2; ++rt)
    #pragma unroll
    for (int t = 0; t < 8; ++t) tri[rt][t] = (f32x4){0.f,0.f,0.f,0.f};

  // wave stages frags f = w*3+p (0..23): f<8 -> a it=f ; else b jt=f-8
  const int f0 = w * 3;
  s16x8 stg[3];
  #pragma unroll
  for (int p = 0; p < 3; ++p) {
    const int f = f0 + p;
    const __hip_bfloat16* src = (f < 8)
        ? aT + (((size_t)s*16 + h*8 + f)*8 + 0)*512
        : bT + (((size_t)s*16 + (f-8))*8 + 0)*512;
    stg[p] = *reinterpret_cast<const s16x8*>(src + lane*8);
  }
  #pragma unroll
  for (int p = 0; p < 3; ++p)
    *reinterpret_cast<s16x8*>(lds + (f0 + p)*1024 + lane*16) = stg[p];
  __syncthreads();

  for (int c = 0; c < 8; ++c) {
    char* const RB = lds + (c & 1) * 24576;        // read buffer
    char* const WB = lds + ((c + 1) & 1) * 24576;  // write buffer (next chunk)
    if (c < 7) {      // issue next-chunk loads early (hide under MFMA)
      #pragma unroll
      for (int p = 0; p < 3; ++p) {
        const int f = f0 + p;
        const __hip_bfloat16* src = (f < 8)
            ? aT + (((size_t)s*16 + h*8 + f)*8 + (c+1))*512
            : bT + (((size_t)s*16 + (f-8))*8 + (c+1))*512;
        stg[p] = *reinterpret_cast<const s16x8*>(src + lane*8);
      }
    }
    const s16x8 ta0 = *reinterpret_cast<const s16x8*>(RB + (r2*2+0)*1024 + lane*16);
    const s16x8 ta1 = *reinterpret_cast<const s16x8*>(RB + (r2*2+1)*1024 + lane*16);
    #pragma unroll
    for (int t = 0; t < 8; ++t) {
      const s16x8 tb = *reinterpret_cast<const s16x8*>(
          RB + (8 + ch*8 + t)*1024 + lane*16);
      tri[0][t] = MFMA16(ta0, tb, tri[0][t]);
      tri[1][t] = MFMA16(ta1, tb, tri[1][t]);
    }
    if (c < 7) {
      #pragma unroll
      for (int p = 0; p < 3; ++p)
        *reinterpret_cast<s16x8*>(WB + (f0 + p)*1024 + lane*16) = stg[p];
    }
    __syncthreads();   // WB writes visible for c+1; RB reads done before c+1 overwrites
  }

  // LN(tri): partial over this wave's 128 cols + partner-wave (w^1) exchange
  float psm[2][4], pss[2][4];
  #pragma unroll
  for (int rt = 0; rt < 2; ++rt)
    #pragma unroll
    for (int q = 0; q < 4; ++q) {
      float sm = 0.f, ss = 0.f;
      #pragma unroll
      for (int t = 0; t < 8; ++t) { const float v = tri[rt][t][q]; sm += v; ss += v*v; }
      #pragma unroll
      for (int m = 1; m < 16; m <<= 1) { sm += __shfl_xor(sm, m); ss += __shfl_xor(ss, m); }
      psm[rt][q] = sm; pss[rt][q] = ss;
    }
  if (l15 == 0) {
    #pragma unroll
    for (int rt = 0; rt < 2; ++rt)
      #pragma unroll
      for (int q = 0; q < 4; ++q) {
        const int idx = ((w*2 + rt)*4 + lh)*4 + q;
        ST[idx*2 + 0] = psm[rt][q];
        ST[idx*2 + 1] = pss[rt][q];
      }
  }
  __syncthreads();
  float mean[2][4], rstd[2][4];
  #pragma unroll
  for (int rt = 0; rt < 2; ++rt)
    #pragma unroll
    for (int q = 0; q < 4; ++q) {
      const int idx = (((w ^ 1)*2 + rt)*4 + lh)*4 + q;
      const float sm = psm[rt][q] + ST[idx*2 + 0];
      const float ss = pss[rt][q] + ST[idx*2 + 1];
      mean[rt][q] = sm * (1.f/256.f);
      rstd[rt][q] = rsqrtf(ss * (1.f/256.f) - mean[rt][q]*mean[rt][q] + 1e-5f);
    }
  __syncthreads();   // ST reads done; STG bufs dead -> SW may overlay
  #pragma unroll
  for (int t = 0; t < 8; ++t) {
    const int j = (ch*8 + t)*16 + l15;
    const float gmv = gamma[j], btv = beta[j];
    #pragma unroll
    for (int rt = 0; rt < 2; ++rt)
      #pragma unroll
      for (int q = 0; q < 4; ++q) {
        const int iloc = r2*32 + rt*16 + lh*4 + q;
        const float v = (tri[rt][t][q] - mean[rt][q]) * rstd[rt][q] * gmv + btv;
        *reinterpret_cast<__hip_bfloat16*>(SW + xad(iloc, j*2)) = __float2bfloat16(v);
      }
  }
  __syncthreads();

  const __hip_bfloat16* const wg = wfrag + 131072;
  const __hip_bfloat16* const wo = wfrag + 196608;

  // ---- Phase G: g = sigmoid(x @ wg^T), packed to bf16 (og released after)
  s16x4 gpk[2][8];
  {
    f32x4 og[2][8];
    #pragma unroll
    for (int rt = 0; rt < 2; ++rt)
      #pragma unroll
      for (int t = 0; t < 8; ++t) og[rt][t] = (f32x4){0.f,0.f,0.f,0.f};
    #pragma unroll
    for (int ks = 0; ks < 8; ++ks) {
      const s16x8 Ax0 = *reinterpret_cast<const s16x8*>(
          xws + (((size_t)s*16 + (h*8 + r2*2 + 0))*8 + ks)*512 + lane*8);
      const s16x8 Ax1 = *reinterpret_cast<const s16x8*>(
          xws + (((size_t)s*16 + (h*8 + r2*2 + 1))*8 + ks)*512 + lane*8);
      #pragma unroll
      for (int t = 0; t < 8; ++t) {
        const s16x8 Bg = *reinterpret_cast<const s16x8*>(
            wg + ((size_t)((ch*8 + t)*8 + ks))*512 + lane*8);
        og[0][t] = MFMA16(Ax0, Bg, og[0][t]);
        og[1][t] = MFMA16(Ax1, Bg, og[1][t]);
      }
    }
    #pragma unroll
    for (int rt = 0; rt < 2; ++rt)
      #pragma unroll
      for (int t = 0; t < 8; ++t) {
        BH4 o;
        #pragma unroll
        for (int q = 0; q < 4; ++q) o.h[q] = __float2bfloat16(sigm(og[rt][t][q]));
        gpk[rt][t] = o.v;
      }
  }

  // ---- Phase O: out = (LN(tri) @ wo^T) * g
  f32x4 oo[2][8];
  #pragma unroll
  for (int rt = 0; rt < 2; ++rt)
    #pragma unroll
    for (int t = 0; t < 8; ++t) oo[rt][t] = (f32x4){0.f,0.f,0.f,0.f};
  #pragma unroll
  for (int ks = 0; ks < 8; ++ks) {
    const s16x8 A0 = *reinterpret_cast<const s16x8*>(
        SW + xad(r2*32 +  0 + l15, ks*64 + lh*16));
    const s16x8 A1 = *reinterpret_cast<const s16x8*>(
        SW + xad(r2*32 + 16 + l15, ks*64 + lh*16));
    #pragma unroll
    for (int t = 0; t < 8; ++t) {
      const s16x8 Bo = *reinterpret_cast<const s16x8*>(
          wo + ((size_t)((ch*8 + t)*8 + ks))*512 + lane*8);
      oo[0][t] = MFMA16(A0, Bo, oo[0][t]);
      oo[1][t] = MFMA16(A1, Bo, oo[1][t]);
    }
  }
  #pragma unroll
  for (int rt = 0; rt < 2; ++rt) {
    #pragma unroll
    for (int t = 0; t < 8; ++t) {
      BH4 gv; gv.v = gpk[rt][t];
      #pragma unroll
      for (int q = 0; q < 4; ++q) {
        const int row = h*128 + r2*32 + rt*16 + lh*4 + q;
        out[((size_t)s*256 + row)*256 + (ch*8 + t)*16 + l15] =
            oo[rt][t][q] * __bfloat162float(gv.h[q]);
      }
    }
  }
}

// ===================== STRATEGY B (fallback, proven ~228 us) =====================
__global__ __launch_bounds__(512, 2) void tri_fused_fb(
    const __hip_bfloat16* __restrict__ xws,
    const __hip_bfloat16* __restrict__ wfrag,
    const float* __restrict__ gamma, const float* __restrict__ beta,
    float* __restrict__ out)
{
  extern __shared__ __align__(16) char lds[];
  char* const XS = lds;
  char* const AC = lds + 32768;
  char* const BC = lds + 49152;
  char* const SW = lds;

  const int raw = blockIdx.x;
  const int xcd = raw & 7, o = raw >> 3;
  const int s   = xcd * 64 + (o >> 1);
  const int h   = o & 1;

  const int tid = threadIdx.x, lane = tid & 63, w = tid >> 6;
  const int l15 = lane & 15, lh = lane >> 4;

  const __hip_bfloat16* const wa = wfrag;
  const __hip_bfloat16* const wb = wfrag + 65536;
  const __hip_bfloat16* const wg = wfrag + 131072;
  const __hip_bfloat16* const wo = wfrag + 196608;
  const __hip_bfloat16* const xs = xws + (size_t)s * 65536;
  const char* const xsb = (const char*)xs;

  f32x4 tri[16];
  #pragma unroll
  for (int jt = 0; jt < 16; ++jt) tri[jt] = (f32x4){0.f,0.f,0.f,0.f};

  {
    s16x8 st[4];
    #pragma unroll
    for (int p = 0; p < 4; ++p)
      st[p] = *reinterpret_cast<const s16x8*>(xsb + p*8192 + tid*16);
    #pragma unroll
    for (int p = 0; p < 4; ++p)
      *reinterpret_cast<s16x8*>(XS + p*8192 + tid*16) = st[p];
  }
  __syncthreads();

  for (int c = 0; c < 4; ++c) {
    {
      const int ct = h*8 + w;
      f32x4 acc[4];
      #pragma unroll
      for (int rt = 0; rt < 4; ++rt) acc[rt] = (f32x4){0.f,0.f,0.f,0.f};
      #pragma unroll
      for (int ks = 0; ks < 8; ++ks) {
        const s16x8 Bf = *reinterpret_cast<const s16x8*>(wa + (((size_t)ct*8 + ks)*64 + lane)*8);
        #pragma unroll
        for (int rt = 0; rt < 4; ++rt) {
          const s16x8 Af = *reinterpret_cast<const s16x8*>(XS + ((rt*8 + ks)*64 + lane)*16);
          acc[rt] = MFMA16(Af, Bf, acc[rt]);
        }
      }
      #pragma unroll
      for (int rt = 0; rt < 4; ++rt) {
        const f32x4 vv = acc[rt];
        BH4 ov;
        #pragma unroll
        for (int q = 0; q < 4; ++q) ov.h[q] = __float2bfloat16(vv[q] * sigm(vv[q]));
        *reinterpret_cast<s16x4*>(AC + cad64(w*16 + l15, rt*16 + lh*4)) = ov.v;
      }
    }
    #pragma unroll
    for (int t = 0; t < 2; ++t) {
      const int ct = 2*w + t;
      f32x4 acc[4];
      #pragma unroll
      for (int rt = 0; rt < 4; ++rt) acc[rt] = (f32x4){0.f,0.f,0.f,0.f};
      #pragma unroll
      for (int ks = 0; ks < 8; ++ks) {
        const s16x8 Bf = *reinterpret_cast<const s16x8*>(wb + (((size_t)ct*8 + ks)*64 + lane)*8);
        #pragma unroll
        for (int rt = 0; rt < 4; ++rt) {
          const s16x8 Af = *reinterpret_cast<const s16x8*>(XS + ((rt*8 + ks)*64 + lane)*16);
          acc[rt] = MFMA16(Af, Bf, acc[rt]);
        }
      }
      #pragma unroll
      for (int rt = 0; rt < 4; ++rt) {
        const f32x4 vv = acc[rt];
        BH4 ov;
        #pragma unroll
        for (int q = 0; q < 4; ++q) ov.h[q] = __float2bfloat16(vv[q] * sigm(vv[q]));
        *reinterpret_cast<s16x4*>(BC + cad64(ct*16 + l15, rt*16 + lh*4)) = ov.v;
      }
    }
    __syncthreads();

    s16x8 st[4];
    if (c < 3) {
      #pragma unroll
      for (int p = 0; p < 4; ++p)
        st[p] = *reinterpret_cast<const s16x8*>(xsb + (c+1)*32768 + p*8192 + tid*16);
    }
    #pragma unroll
    for (int kss = 0; kss < 2; ++kss) {
      const s16x8 ta = *reinterpret_cast<const s16x8*>(AC + cad64(w*16 + l15, kss*32 + lh*8));
      #pragma unroll
      for (int jt = 0; jt < 16; ++jt) {
        const s16x8 tb = *reinterpret_cast<const s16x8*>(BC + cad64(jt*16 + l15, kss*32 + lh*8));
        tri[jt] = MFMA16(ta, tb, tri[jt]);
      }
    }
    if (c < 3) {
      #pragma unroll
      for (int p = 0; p < 4; ++p)
        *reinterpret_cast<s16x8*>(XS + p*8192 + tid*16) = st[p];
    }
    __syncthreads();
  }

  {
    float mean[4], rstd[4];
    #pragma unroll
    for (int q = 0; q < 4; ++q) {
      float sm = 0.f, ss = 0.f;
      #pragma unroll
      for (int jt = 0; jt < 16; ++jt) { const float x = tri[jt][q]; sm += x; ss += x*x; }
      #pragma unroll
      for (int m = 1; m < 16; m <<= 1) { sm += __shfl_xor(sm, m); ss += __shfl_xor(ss, m); }
      mean[q] = sm * (1.f/256.f);
      rstd[q] = rsqrtf(ss * (1.f/256.f) - mean[q]*mean[q] + 1e-5f);
    }
    #pragma unroll
    for (int jt = 0; jt < 16; ++jt) {
      const float gm = gamma[jt*16 + l15];
      const float bt = beta [jt*16 + l15];
      #pragma unroll
      for (int q = 0; q < 4; ++q) {
        const float vv = (tri[jt][q] - mean[q]) * rstd[q] * gm + bt;
        *reinterpret_cast<__hip_bfloat16*>(
            SW + xad(w*16 + lh*4 + q, (jt*16 + l15)*2)) = __float2bfloat16(vv);
      }
    }
  }
  __syncthreads();

  #pragma unroll
  for (int half = 0; half < 2; ++half) {
    #pragma unroll
    for (int t = 0; t < 2; ++t) {
      const int ct = 2*w + t;
      f32x4 og[4], oo[4];
      #pragma unroll
      for (int rt = 0; rt < 4; ++rt) { og[rt] = (f32x4){0.f,0.f,0.f,0.f}; oo[rt] = (f32x4){0.f,0.f,0.f,0.f}; }
      #pragma unroll
      for (int ks = 0; ks < 8; ++ks) {
        const s16x8 Bg = *reinterpret_cast<const s16x8*>(wg + (((size_t)ct*8 + ks)*64 + lane)*8);
        const s16x8 Bo = *reinterpret_cast<const s16x8*>(wo + (((size_t)ct*8 + ks)*64 + lane)*8);
        #pragma unroll
        for (int rt = 0; rt < 4; ++rt) {
          const int rtg = h*8 + half*4 + rt;
          const s16x8 Ax  = *reinterpret_cast<const s16x8*>(xs + (((size_t)rtg*8 + ks)*64 + lane)*8);
          const s16x8 Aln = *reinterpret_cast<const s16x8*>(
              SW + xad(half*64 + rt*16 + l15, ks*64 + lh*16));
          og[rt] = MFMA16(Ax,  Bg, og[rt]);
          oo[rt] = MFMA16(Aln, Bo, oo[rt]);
        }
      }
      #pragma unroll
      for (int rt = 0; rt < 4; ++rt) {
        #pragma unroll
        for (int q = 0; q < 4; ++q) {
          const int row = h*128 + half*64 + rt*16 + lh*4 + q;
          out[(size_t)s*65536 + (size_t)row*256 + ct*16 + l15] =
              oo[rt][q] * sigm(og[rt][q]);
        }
      }
    }
  }
}

extern "C" void kernel_launch(void* const* d_in, const int* in_sizes, int n_in,
                              void* d_out, int out_size, void* d_ws, size_t ws_size,
                              hipStream_t stream) {
  const float* pair   = (const float*)d_in[0];
  const float* w_in   = (const float*)d_in[1];
  const float* w_gate = (const float*)d_in[2];
  const float* w_out  = (const float*)d_in[3];
  const float* gamma  = (const float*)d_in[4];
  const float* beta   = (const float*)d_in[5];
  float* out = (float*)d_out;

  (void)in_sizes; (void)n_in; (void)out_size;

  __hip_bfloat16* wfrag = (__hip_bfloat16*)d_ws;                    // 512 KB
  __hip_bfloat16* xws   = (__hip_bfloat16*)((char*)d_ws + 524288);  // 67 MB

  wfrag_kernel<<<dim3(128, 4), 64, 0, stream>>>(w_in, w_gate, w_out, wfrag);
  ln_kernel<<<8192, 256, 0, stream>>>(pair, gamma, beta, xws);

  if (ws_size >= 201850880ULL) {
    // Strategy A: decomposed streaming pipeline
    __hip_bfloat16* aT = (__hip_bfloat16*)((char*)d_ws + 524288 + 67108864);
    __hip_bfloat16* bT = (__hip_bfloat16*)((char*)d_ws + 524288 + 2*67108864);
    hipFuncSetAttribute(reinterpret_cast<const void*>(k3_tri),
                        hipFuncAttributeMaxDynamicSharedMemorySize, 67584);
    k2_ab<<<512, 512, 0, stream>>>(xws, wfrag, aT, bT);
    k3_tri<<<1024, 512, 67584, stream>>>(aT, bT, xws, wfrag, gamma, beta, out);
  } else {
    // Strategy B: proven fused pipeline (R3)
    hipFuncSetAttribute(reinterpret_cast<const void*>(tri_fused_fb),
                        hipFuncAttributeMaxDynamicSharedMemorySize, 81920);
    tri_fused_fb<<<1024, 512, 81920, stream>>>(xws, wfrag, gamma, beta, out);
  }
}

// Round 11
// 229.209 us; speedup vs baseline: 1.9621x; 1.9621x over previous
//
#include <hip/hip_runtime.h>
#include <hip/hip_bf16.h>

typedef __attribute__((ext_vector_type(4))) float  f32x4;
typedef __attribute__((ext_vector_type(8))) short  s16x8;
typedef __attribute__((ext_vector_type(4))) short  s16x4;

union BH4 { s16x4 v; __hip_bfloat16 h[4]; };
union BH8 { s16x8 v; __hip_bfloat16 h[8]; };

#define MFMA16(A,B,C) __builtin_amdgcn_mfma_f32_16x16x32_bf16((A),(B),(C),0,0,0)

__device__ __forceinline__ float sigm(float x) { return 1.0f / (1.0f + __expf(-x)); }

// [rows][256] bf16 (512 B rows): XOR row into 16B slot (bank-conflict fix)
__device__ __forceinline__ int xad(int r, int byteInRow) {
  return ((r << 9) + byteInRow) ^ ((r & 7) << 4);
}
// chunk buffers: [rows][64] bf16 (128 B rows): slot16 ^= (i&7)   (fallback path)
__device__ __forceinline__ int cad64(int i, int k) {
  return (i << 7) + ((((k >> 3) ^ (i & 7)) << 4) | ((k & 7) << 1));
}

// fp32 weight [256][256] -> bf16 MFMA B-fragment order:
// dst[((m*16+ct)*8+ks)*512 + lane*8 + j] = w[ct*16+(lane&15)][ks*32+(lane>>4)*8+j]
__global__ void wfrag_kernel(const float* __restrict__ w_in,
                             const float* __restrict__ w_gate,
                             const float* __restrict__ w_out,
                             __hip_bfloat16* __restrict__ dst) {
  const int lane = threadIdx.x;         // 64
  const int fid  = blockIdx.x;          // 0..127 = ct*8+ks
  const int m    = blockIdx.y;          // 0:wa 1:wb 2:wg 3:wo
  const float* src = (m == 0) ? w_in : (m == 1) ? (w_in + 65536)
                    : (m == 2) ? w_gate : w_out;
  const int e  = (fid >> 3) * 16 + (lane & 15);
  const int d0 = (fid & 7) * 32 + (lane >> 4) * 8;
  BH8 u;
  #pragma unroll
  for (int j = 0; j < 8; ++j) u.h[j] = __float2bfloat16(src[e * 256 + d0 + j]);
  *reinterpret_cast<s16x8*>(dst + (size_t)m * 65536 + ((size_t)fid * 64 + lane) * 8) = u.v;
}

// K1: x = LN(pair) -> xws in A-fragment order (proven):
// xws[((s*16+rt)*8+ks)*512 + lane*8 + j] = x[s][rt*16+(lane&15)][ks*32+(lane>>4)*8+j]
__global__ __launch_bounds__(256) void ln_kernel(
    const float* __restrict__ pair, const float* __restrict__ gamma,
    const float* __restrict__ beta, __hip_bfloat16* __restrict__ xws)
{
  __shared__ char Xl[8192];
  const int t  = threadIdx.x;
  const int s  = blockIdx.x >> 4;
  const int rt = blockIdx.x & 15;
  const int r  = t >> 4;
  const int c0 = (t & 15) * 16;
  const float* src = pair + (((size_t)s * 256 + rt * 16 + r) * 256 + c0);
  float v[16];
  #pragma unroll
  for (int i = 0; i < 4; ++i) {
    const float4 f = *reinterpret_cast<const float4*>(src + i * 4);
    v[i*4+0]=f.x; v[i*4+1]=f.y; v[i*4+2]=f.z; v[i*4+3]=f.w;
  }
  float sm = 0.f, ss = 0.f;
  #pragma unroll
  for (int i = 0; i < 16; ++i) { sm += v[i]; ss += v[i]*v[i]; }
  #pragma unroll
  for (int m = 1; m < 16; m <<= 1) { sm += __shfl_xor(sm, m); ss += __shfl_xor(ss, m); }
  const float mean = sm * (1.f/256.f);
  const float rstd = rsqrtf(ss * (1.f/256.f) - mean*mean + 1e-5f);
  #pragma unroll
  for (int i = 0; i < 4; ++i) {
    const float4 gm = *reinterpret_cast<const float4*>(gamma + c0 + i*4);
    const float4 bt = *reinterpret_cast<const float4*>(beta  + c0 + i*4);
    BH4 o;
    o.h[0] = __float2bfloat16((v[i*4+0]-mean)*rstd*gm.x + bt.x);
    o.h[1] = __float2bfloat16((v[i*4+1]-mean)*rstd*gm.y + bt.y);
    o.h[2] = __float2bfloat16((v[i*4+2]-mean)*rstd*gm.z + bt.z);
    o.h[3] = __float2bfloat16((v[i*4+3]-mean)*rstd*gm.w + bt.w);
    *reinterpret_cast<s16x4*>(Xl + xad(r, (c0 + i*4)*2)) = o.v;
  }
  __syncthreads();
  #pragma unroll
  for (int p = 0; p < 2; ++p) {
    const int u  = t + p * 256;
    const int ks = u >> 6;
    const int lp = u & 63;
    const s16x8 f = *reinterpret_cast<const s16x8*>(
        Xl + xad(lp & 15, ks*64 + ((lp>>4)&3)*16));
    *reinterpret_cast<s16x8*>(xws + ((((size_t)s*16 + rt)*8 + ks)*64 + lp)*8) = f;
  }
}

// ===================== STRATEGY A =====================
// K2: per-slice block (512 thr, 8 waves). Wave w owns token row-tiles 2w,2w+1
// (x A-frags from xws in regs). Weights broadcast via 2x8KB LDS double buffer.
// 48 cg tiles: a (SiLU->aT frags), b (SiLU->bT frags), g (sigmoid->gws C-layout).
// NOTE: gws aliases xws — safe: each wave reads its own 16KB xws range into regs
// (waited long before cg>=32) and writes only the SAME 16KB range of gws.
__global__ __launch_bounds__(512, 4) void k2_abg(
    const __hip_bfloat16* __restrict__ xws,
    const __hip_bfloat16* __restrict__ wfrag,
    __hip_bfloat16* __restrict__ aT, __hip_bfloat16* __restrict__ bT,
    __hip_bfloat16* __restrict__ gws)
{
  __shared__ __align__(16) char wb2[2][8192];
  const int raw = blockIdx.x;                    // 512 blocks
  const int s   = (raw & 7) * 64 + (raw >> 3);   // XCD-pinned slice
  const int tid = threadIdx.x, lane = tid & 63, w = tid >> 6;
  const int l15 = lane & 15, lh = lane >> 4;

  // x A-frags for this wave's two row-tiles (regs/AGPR, 64)
  s16x8 xr[2][8];
  #pragma unroll
  for (int rt = 0; rt < 2; ++rt)
    #pragma unroll
    for (int ks = 0; ks < 8; ++ks)
      xr[rt][ks] = *reinterpret_cast<const s16x8*>(
          xws + (((size_t)s*16 + (w*2 + rt))*8 + ks)*512 + lane*8);

  // preload cg=0 weight chunk (8 KB) into buffer 0
  {
    const s16x8 v0 = *reinterpret_cast<const s16x8*>(wfrag + tid*8);
    *reinterpret_cast<s16x8*>(&wb2[0][tid*16]) = v0;
  }
  __syncthreads();

  #pragma unroll 1
  for (int cg = 0; cg < 48; ++cg) {   // 0..15 a, 16..31 b, 32..47 g
    const int cur = cg & 1;
    s16x8 pf;
    if (cg < 47)
      pf = *reinterpret_cast<const s16x8*>(wfrag + (size_t)(cg+1)*4096 + tid*8);

    const int m  = cg >> 4;
    const int ct = cg & 15;
    f32x4 acc0 = (f32x4){0.f,0.f,0.f,0.f};
    f32x4 acc1 = (f32x4){0.f,0.f,0.f,0.f};
    #pragma unroll
    for (int ks = 0; ks < 8; ++ks) {
      const s16x8 Bf = *reinterpret_cast<const s16x8*>(&wb2[cur][ks*1024 + lane*16]);
      acc0 = MFMA16(xr[0][ks], Bf, acc0);
      acc1 = MFMA16(xr[1][ks], Bf, acc1);
    }
    if (m < 2) {
      __hip_bfloat16* const dst = (m == 0) ? aT : bT;
      #pragma unroll
      for (int rt = 0; rt < 2; ++rt) {
        const f32x4 a = rt ? acc1 : acc0;
        BH4 o;
        #pragma unroll
        for (int q = 0; q < 4; ++q) o.h[q] = __float2bfloat16(a[q] * sigm(a[q]));
        const int lane2 = l15 + 16 * ((rt*2 + (lh >> 1)) & 3);
        // frag (s, it=ct, kt=w); value = act[k = w*32+rt*16+lh*4+q][i = ct*16+l15]
        *reinterpret_cast<s16x4*>(
            dst + (((size_t)s*16 + ct)*8 + w)*512 + lane2*8 + (lh & 1)*4) = o.v;
      }
    } else {
      #pragma unroll
      for (int rt = 0; rt < 2; ++rt) {
        const f32x4 a = rt ? acc1 : acc0;
        BH4 o;
        #pragma unroll
        for (int q = 0; q < 4; ++q) o.h[q] = __float2bfloat16(sigm(a[q]));
        const int rtg = w * 2 + rt;
        // C-layout: value = g[row=rtg*16+lh*4+q][col=ct*16+l15]
        *reinterpret_cast<s16x4*>(
            gws + (((size_t)s*16 + rtg)*16 + ct)*256 + lane*4) = o.v;
      }
    }
    if (cg < 47)
      *reinterpret_cast<s16x8*>(&wb2[cur ^ 1][tid*16]) = pf;
    __syncthreads();
  }
}

// K3 v2: half-slice block (128 i x 256 j), 512 thr, 8 waves.
// Wave (r2=w>>1, ch=w&1): tri rows r2*32..+32, cols ch*128..+128.
// tri = aT.bT with fragments read DIRECTLY from L2 (no LDS staging, no
// tri-loop barriers); in-reg LN (ST overlays SW head, used before SW);
// single O phase: out = (LN(tri) @ wo^T) * g(precomputed).
__global__ __launch_bounds__(512, 4) void k3_tri(
    const __hip_bfloat16* __restrict__ aT, const __hip_bfloat16* __restrict__ bT,
    const __hip_bfloat16* __restrict__ gws, const __hip_bfloat16* __restrict__ wfrag,
    const float* __restrict__ gamma, const float* __restrict__ beta,
    float* __restrict__ out)
{
  __shared__ __align__(16) char lds[65536];      // SW: ln(tri) [128][256] bf16
  char*  const SW = lds;
  float* const ST = (float*)lds;                 // 2KB stats overlay (pre-SW use)

  const int raw = blockIdx.x;                    // 1024 blocks
  const int s   = (raw & 7) * 64 + ((raw >> 3) >> 1);
  const int h   = (raw >> 3) & 1;
  const int tid = threadIdx.x, lane = tid & 63, w = tid >> 6;
  const int l15 = lane & 15, lh = lane >> 4;
  const int r2 = w >> 1, ch = w & 1;

  f32x4 tri[2][8];
  #pragma unroll
  for (int rt = 0; rt < 2; ++rt)
    #pragma unroll
    for (int t = 0; t < 8; ++t) tri[rt][t] = (f32x4){0.f,0.f,0.f,0.f};

  // fragment bases: aT/bT[(s*16 + tile)*8 + chunk]*512 + lane*8
  const __hip_bfloat16* const a0b = aT + ((size_t)s*16 + h*8 + r2*2 + 0)*8*512 + lane*8;
  const __hip_bfloat16* const a1b = aT + ((size_t)s*16 + h*8 + r2*2 + 1)*8*512 + lane*8;
  const __hip_bfloat16* const bbb = bT + ((size_t)s*16 + ch*8)*8*512 + lane*8;

  #pragma unroll 1
  for (int c = 0; c < 8; ++c) {
    const s16x8 ta0 = *reinterpret_cast<const s16x8*>(a0b + (size_t)c*512);
    const s16x8 ta1 = *reinterpret_cast<const s16x8*>(a1b + (size_t)c*512);
    #pragma unroll
    for (int t = 0; t < 8; ++t) {
      const s16x8 tb = *reinterpret_cast<const s16x8*>(bbb + ((size_t)t*8 + c)*512);
      tri[0][t] = MFMA16(ta0, tb, tri[0][t]);
      tri[1][t] = MFMA16(ta1, tb, tri[1][t]);
    }
  }

  // LN(tri): partial over this wave's 128 cols + partner-wave (w^1) exchange
  float psm[2][4], pss[2][4];
  #pragma unroll
  for (int rt = 0; rt < 2; ++rt)
    #pragma unroll
    for (int q = 0; q < 4; ++q) {
      float sm = 0.f, ss = 0.f;
      #pragma unroll
      for (int t = 0; t < 8; ++t) { const float v = tri[rt][t][q]; sm += v; ss += v*v; }
      #pragma unroll
      for (int m = 1; m < 16; m <<= 1) { sm += __shfl_xor(sm, m); ss += __shfl_xor(ss, m); }
      psm[rt][q] = sm; pss[rt][q] = ss;
    }
  if (l15 == 0) {
    #pragma unroll
    for (int rt = 0; rt < 2; ++rt)
      #pragma unroll
      for (int q = 0; q < 4; ++q) {
        const int idx = ((w*2 + rt)*4 + lh)*4 + q;
        ST[idx*2 + 0] = psm[rt][q];
        ST[idx*2 + 1] = pss[rt][q];
      }
  }
  __syncthreads();
  float mean[2][4], rstd[2][4];
  #pragma unroll
  for (int rt = 0; rt < 2; ++rt)
    #pragma unroll
    for (int q = 0; q < 4; ++q) {
      const int idx = (((w ^ 1)*2 + rt)*4 + lh)*4 + q;
      const float sm = psm[rt][q] + ST[idx*2 + 0];
      const float ss = pss[rt][q] + ST[idx*2 + 1];
      mean[rt][q] = sm * (1.f/256.f);
      rstd[rt][q] = rsqrtf(ss * (1.f/256.f) - mean[rt][q]*mean[rt][q] + 1e-5f);
    }
  __syncthreads();   // ST reads done -> SW may overwrite
  #pragma unroll
  for (int t = 0; t < 8; ++t) {
    const int j = (ch*8 + t)*16 + l15;
    const float gmv = gamma[j], btv = beta[j];
    #pragma unroll
    for (int rt = 0; rt < 2; ++rt)
      #pragma unroll
      for (int q = 0; q < 4; ++q) {
        const int iloc = r2*32 + rt*16 + lh*4 + q;
        const float v = (tri[rt][t][q] - mean[rt][q]) * rstd[rt][q] * gmv + btv;
        *reinterpret_cast<__hip_bfloat16*>(SW + xad(iloc, j*2)) = __float2bfloat16(v);
      }
  }
  __syncthreads();

  // O phase: out = (LN(tri) @ wo^T) * g  (R8-proven structure)
  const __hip_bfloat16* const wo = wfrag + 196608;
  f32x4 oo[2][8];
  #pragma unroll
  for (int rt = 0; rt < 2; ++rt)
    #pragma unroll
    for (int t = 0; t < 8; ++t) oo[rt][t] = (f32x4){0.f,0.f,0.f,0.f};
  #pragma unroll
  for (int ks = 0; ks < 8; ++ks) {
    const s16x8 A0 = *reinterpret_cast<const s16x8*>(
        SW + xad(r2*32 +  0 + l15, ks*64 + lh*16));
    const s16x8 A1 = *reinterpret_cast<const s16x8*>(
        SW + xad(r2*32 + 16 + l15, ks*64 + lh*16));
    #pragma unroll
    for (int t = 0; t < 8; ++t) {
      const s16x8 Bo = *reinterpret_cast<const s16x8*>(
          wo + ((size_t)((ch*8 + t)*8 + ks))*512 + lane*8);
      oo[0][t] = MFMA16(A0, Bo, oo[0][t]);
      oo[1][t] = MFMA16(A1, Bo, oo[1][t]);
    }
  }
  #pragma unroll
  for (int rt = 0; rt < 2; ++rt) {
    const int rtg = h*8 + r2*2 + rt;
    #pragma unroll
    for (int t = 0; t < 8; ++t) {
      BH4 gv;
      gv.v = *reinterpret_cast<const s16x4*>(
          gws + (((size_t)s*16 + rtg)*16 + (ch*8 + t))*256 + lane*4);
      #pragma unroll
      for (int q = 0; q < 4; ++q) {
        const int row = h*128 + r2*32 + rt*16 + lh*4 + q;
        out[((size_t)s*256 + row)*256 + (ch*8 + t)*16 + l15] =
            oo[rt][t][q] * __bfloat162float(gv.h[q]);
      }
    }
  }
}

// ===================== STRATEGY B (fallback, proven ~228 us) =====================
__global__ __launch_bounds__(512, 2) void tri_fused_fb(
    const __hip_bfloat16* __restrict__ xws,
    const __hip_bfloat16* __restrict__ wfrag,
    const float* __restrict__ gamma, const float* __restrict__ beta,
    float* __restrict__ out)
{
  extern __shared__ __align__(16) char lds[];
  char* const XS = lds;
  char* const AC = lds + 32768;
  char* const BC = lds + 49152;
  char* const SW = lds;

  const int raw = blockIdx.x;
  const int xcd = raw & 7, o = raw >> 3;
  const int s   = xcd * 64 + (o >> 1);
  const int h   = o & 1;

  const int tid = threadIdx.x, lane = tid & 63, w = tid >> 6;
  const int l15 = lane & 15, lh = lane >> 4;

  const __hip_bfloat16* const wa = wfrag;
  const __hip_bfloat16* const wb = wfrag + 65536;
  const __hip_bfloat16* const wg = wfrag + 131072;
  const __hip_bfloat16* const wo = wfrag + 196608;
  const __hip_bfloat16* const xs = xws + (size_t)s * 65536;
  const char* const xsb = (const char*)xs;

  f32x4 tri[16];
  #pragma unroll
  for (int jt = 0; jt < 16; ++jt) tri[jt] = (f32x4){0.f,0.f,0.f,0.f};

  {
    s16x8 st[4];
    #pragma unroll
    for (int p = 0; p < 4; ++p)
      st[p] = *reinterpret_cast<const s16x8*>(xsb + p*8192 + tid*16);
    #pragma unroll
    for (int p = 0; p < 4; ++p)
      *reinterpret_cast<s16x8*>(XS + p*8192 + tid*16) = st[p];
  }
  __syncthreads();

  for (int c = 0; c < 4; ++c) {
    {
      const int ct = h*8 + w;
      f32x4 acc[4];
      #pragma unroll
      for (int rt = 0; rt < 4; ++rt) acc[rt] = (f32x4){0.f,0.f,0.f,0.f};
      #pragma unroll
      for (int ks = 0; ks < 8; ++ks) {
        const s16x8 Bf = *reinterpret_cast<const s16x8*>(wa + (((size_t)ct*8 + ks)*64 + lane)*8);
        #pragma unroll
        for (int rt = 0; rt < 4; ++rt) {
          const s16x8 Af = *reinterpret_cast<const s16x8*>(XS + ((rt*8 + ks)*64 + lane)*16);
          acc[rt] = MFMA16(Af, Bf, acc[rt]);
        }
      }
      #pragma unroll
      for (int rt = 0; rt < 4; ++rt) {
        const f32x4 vv = acc[rt];
        BH4 ov;
        #pragma unroll
        for (int q = 0; q < 4; ++q) ov.h[q] = __float2bfloat16(vv[q] * sigm(vv[q]));
        *reinterpret_cast<s16x4*>(AC + cad64(w*16 + l15, rt*16 + lh*4)) = ov.v;
      }
    }
    #pragma unroll
    for (int t = 0; t < 2; ++t) {
      const int ct = 2*w + t;
      f32x4 acc[4];
      #pragma unroll
      for (int rt = 0; rt < 4; ++rt) acc[rt] = (f32x4){0.f,0.f,0.f,0.f};
      #pragma unroll
      for (int ks = 0; ks < 8; ++ks) {
        const s16x8 Bf = *reinterpret_cast<const s16x8*>(wb + (((size_t)ct*8 + ks)*64 + lane)*8);
        #pragma unroll
        for (int rt = 0; rt < 4; ++rt) {
          const s16x8 Af = *reinterpret_cast<const s16x8*>(XS + ((rt*8 + ks)*64 + lane)*16);
          acc[rt] = MFMA16(Af, Bf, acc[rt]);
        }
      }
      #pragma unroll
      for (int rt = 0; rt < 4; ++rt) {
        const f32x4 vv = acc[rt];
        BH4 ov;
        #pragma unroll
        for (int q = 0; q < 4; ++q) ov.h[q] = __float2bfloat16(vv[q] * sigm(vv[q]));
        *reinterpret_cast<s16x4*>(BC + cad64(ct*16 + l15, rt*16 + lh*4)) = ov.v;
      }
    }
    __syncthreads();

    s16x8 st[4];
    if (c < 3) {
      #pragma unroll
      for (int p = 0; p < 4; ++p)
        st[p] = *reinterpret_cast<const s16x8*>(xsb + (c+1)*32768 + p*8192 + tid*16);
    }
    #pragma unroll
    for (int kss = 0; kss < 2; ++kss) {
      const s16x8 ta = *reinterpret_cast<const s16x8*>(AC + cad64(w*16 + l15, kss*32 + lh*8));
      #pragma unroll
      for (int jt = 0; jt < 16; ++jt) {
        const s16x8 tb = *reinterpret_cast<const s16x8*>(BC + cad64(jt*16 + l15, kss*32 + lh*8));
        tri[jt] = MFMA16(ta, tb, tri[jt]);
      }
    }
    if (c < 3) {
      #pragma unroll
      for (int p = 0; p < 4; ++p)
        *reinterpret_cast<s16x8*>(XS + p*8192 + tid*16) = st[p];
    }
    __syncthreads();
  }

  {
    float mean[4], rstd[4];
    #pragma unroll
    for (int q = 0; q < 4; ++q) {
      float sm = 0.f, ss = 0.f;
      #pragma unroll
      for (int jt = 0; jt < 16; ++jt) { const float x = tri[jt][q]; sm += x; ss += x*x; }
      #pragma unroll
      for (int m = 1; m < 16; m <<= 1) { sm += __shfl_xor(sm, m); ss += __shfl_xor(ss, m); }
      mean[q] = sm * (1.f/256.f);
      rstd[q] = rsqrtf(ss * (1.f/256.f) - mean[q]*mean[q] + 1e-5f);
    }
    #pragma unroll
    for (int jt = 0; jt < 16; ++jt) {
      const float gm = gamma[jt*16 + l15];
      const float bt = beta [jt*16 + l15];
      #pragma unroll
      for (int q = 0; q < 4; ++q) {
        const float vv = (tri[jt][q] - mean[q]) * rstd[q] * gm + bt;
        *reinterpret_cast<__hip_bfloat16*>(
            SW + xad(w*16 + lh*4 + q, (jt*16 + l15)*2)) = __float2bfloat16(vv);
      }
    }
  }
  __syncthreads();

  #pragma unroll
  for (int half = 0; half < 2; ++half) {
    #pragma unroll
    for (int t = 0; t < 2; ++t) {
      const int ct = 2*w + t;
      f32x4 og[4], oo[4];
      #pragma unroll
      for (int rt = 0; rt < 4; ++rt) { og[rt] = (f32x4){0.f,0.f,0.f,0.f}; oo[rt] = (f32x4){0.f,0.f,0.f,0.f}; }
      #pragma unroll
      for (int ks = 0; ks < 8; ++ks) {
        const s16x8 Bg = *reinterpret_cast<const s16x8*>(wg + (((size_t)ct*8 + ks)*64 + lane)*8);
        const s16x8 Bo = *reinterpret_cast<const s16x8*>(wo + (((size_t)ct*8 + ks)*64 + lane)*8);
        #pragma unroll
        for (int rt = 0; rt < 4; ++rt) {
          const int rtg = h*8 + half*4 + rt;
          const s16x8 Ax  = *reinterpret_cast<const s16x8*>(xs + (((size_t)rtg*8 + ks)*64 + lane)*8);
          const s16x8 Aln = *reinterpret_cast<const s16x8*>(
              SW + xad(half*64 + rt*16 + l15, ks*64 + lh*16));
          og[rt] = MFMA16(Ax,  Bg, og[rt]);
          oo[rt] = MFMA16(Aln, Bo, oo[rt]);
        }
      }
      #pragma unroll
      for (int rt = 0; rt < 4; ++rt) {
        #pragma unroll
        for (int q = 0; q < 4; ++q) {
          const int row = h*128 + half*64 + rt*16 + lh*4 + q;
          out[(size_t)s*65536 + (size_t)row*256 + ct*16 + l15] =
              oo[rt][q] * sigm(og[rt][q]);
        }
      }
    }
  }
}

extern "C" void kernel_launch(void* const* d_in, const int* in_sizes, int n_in,
                              void* d_out, int out_size, void* d_ws, size_t ws_size,
                              hipStream_t stream) {
  const float* pair   = (const float*)d_in[0];
  const float* w_in   = (const float*)d_in[1];
  const float* w_gate = (const float*)d_in[2];
  const float* w_out  = (const float*)d_in[3];
  const float* gamma  = (const float*)d_in[4];
  const float* beta   = (const float*)d_in[5];
  float* out = (float*)d_out;

  (void)in_sizes; (void)n_in; (void)out_size;

  __hip_bfloat16* wfrag = (__hip_bfloat16*)d_ws;                    // 512 KB
  __hip_bfloat16* xws   = (__hip_bfloat16*)((char*)d_ws + 524288);  // 67 MB

  wfrag_kernel<<<dim3(128, 4), 64, 0, stream>>>(w_in, w_gate, w_out, wfrag);
  ln_kernel<<<8192, 256, 0, stream>>>(pair, gamma, beta, xws);

  if (ws_size >= 201850880ULL) {
    // Strategy A: decomposed streaming pipeline; gws aliases xws (safe, see k2)
    __hip_bfloat16* aT  = (__hip_bfloat16*)((char*)d_ws + 524288 + 67108864);
    __hip_bfloat16* bT  = (__hip_bfloat16*)((char*)d_ws + 524288 + 2*67108864);
    __hip_bfloat16* gws = xws;
    k2_abg<<<512, 512, 0, stream>>>(xws, wfrag, aT, bT, gws);
    k3_tri<<<1024, 512, 0, stream>>>(aT, bT, gws, wfrag, gamma, beta, out);
  } else {
    // Strategy B: proven fused pipeline (R3)
    hipFuncSetAttribute(reinterpret_cast<const void*>(tri_fused_fb),
                        hipFuncAttributeMaxDynamicSharedMemorySize, 81920);
    tri_fused_fb<<<1024, 512, 81920, stream>>>(xws, wfrag, gamma, beta, out);
  }
}